// Round 11
// baseline (45.596 us; speedup 1.0000x reference)
//
#include <hip/hip_runtime.h>
#include <hip/hip_bf16.h>

// Siren fused, 32x32x16 MFMA, zero-LDS, double sigma-cancellation.
// R11: activation sines moved OFF the trans pipe. v_sin_f32 measures ~25-32
// cyc/wave64 on gfx950 (fitted from R3/R8 timings) => R8 was trans-bound.
// Activations (64 sins/point) now use a deg-7 odd minimax poly in revolutions
// (Chebyshev-Bessel coeffs, |err| <= 2*J9(pi) ~ 2.6e-4 << bf16 quant 2e-3):
//   x = r - rndne(r); sin(2*pi*r) ~ x*(d1 + x2*(d3 + x2*(d5 + x2*d7)))
// 7 full-rate VALU ops vs ~27+ trans cyc. Only the 6 enc seeds/lane stay on
// v_sin/v_cos. Structure otherwise = R8 (best measured, 35.6us).

typedef short short8 __attribute__((ext_vector_type(8)));
typedef float f32x16 __attribute__((ext_vector_type(16)));

#define THREADS 256
#define INV2PI 0.15915494309189535f

__device__ __forceinline__ unsigned packbf(float lo, float hi) {
    union { __hip_bfloat162 h; unsigned u; } v;
    v.h = __float22bfloat162_rn(make_float2(lo, hi));
    return v.u;
}

// sin(2*pi*r) via deg-7 odd minimax on the FMA pipe (r in revolutions, any range)
__device__ __forceinline__ float sin2pi(float r) {
    float x = r - __builtin_rintf(r);       // v_rndne + v_sub -> [-0.5, 0.5]
    float y = x * x;
    float p = fmaf(y, -56.033280f, 77.910016f);
    p = fmaf(y, p, -41.090432f);
    p = fmaf(y, p, 6.2784272f);
    return x * p;
}

// ---- bake per-lane A fragments (W^T scaled by 1/2pi), 32x32x16 shape ----
// ws (uint4): [0..191]   A0 frags, t=0..2 : elem e of lane(h,c) = W0[h*24+8t+e][c]/2pi
//             [192..319] A1 frags, t=0..1 : elem e = W1[(e&3)+8*(e>>2)+4h+16t][c]/2pi
//             [320..575] W2 per-lane 4x float4: w2v[i] = W2[8i+4h .. +3]
__global__ void build_frags(const float* __restrict__ W0,
                            const float* __restrict__ W1,
                            const float* __restrict__ W2,
                            uint4* __restrict__ ws) {
    int l = threadIdx.x;
    if (l >= 64) return;
    int h = l >> 5, c = l & 31;

#pragma unroll
    for (int t = 0; t < 3; ++t) {
        float ev[8];
#pragma unroll
        for (int e = 0; e < 8; ++e) ev[e] = W0[(h * 24 + 8 * t + e) * 32 + c] * INV2PI;
        ws[t * 64 + l] = make_uint4(packbf(ev[0], ev[1]), packbf(ev[2], ev[3]),
                                    packbf(ev[4], ev[5]), packbf(ev[6], ev[7]));
    }
#pragma unroll
    for (int t = 0; t < 2; ++t) {
        float ev[8];
#pragma unroll
        for (int e = 0; e < 8; ++e) {
            int k = (e & 3) + 8 * (e >> 2) + 4 * h + 16 * t;
            ev[e] = W1[k * 32 + c] * INV2PI;
        }
        ws[(3 + t) * 64 + l] = make_uint4(packbf(ev[0], ev[1]), packbf(ev[2], ev[3]),
                                          packbf(ev[4], ev[5]), packbf(ev[6], ev[7]));
    }
    float4* w2v = (float4*)(ws + 320);
#pragma unroll
    for (int i = 0; i < 4; ++i)
        w2v[l * 4 + i] = make_float4(W2[8 * i + 4 * h + 0], W2[8 * i + 4 * h + 1],
                                     W2[8 * i + 4 * h + 2], W2[8 * i + 4 * h + 3]);
}

__global__ __launch_bounds__(THREADS, 4) void siren_mfma_kernel(
    const float* __restrict__ xf,     // [N][2] flat
    const uint4* __restrict__ wf,
    float* __restrict__ out,
    int n)
{
    const int lane = threadIdx.x & 63;
    const int wid = threadIdx.x >> 6;
    const int q = lane & 31, h = lane >> 5;
    const int p0 = blockIdx.x * THREADS + wid * 64;
    if (p0 >= n) return;

    union U { uint4 u; short8 v; };
    short8 a0[3], a1[2];
#pragma unroll
    for (int t = 0; t < 3; ++t) { U tt; tt.u = wf[t * 64 + lane]; a0[t] = tt.v; }
#pragma unroll
    for (int t = 0; t < 2; ++t) { U tt; tt.u = wf[(3 + t) * 64 + lane]; a1[t] = tt.v; }
    float4 w2v[4];
#pragma unroll
    for (int i = 0; i < 4; ++i) w2v[i] = ((const float4*)(wf + 320))[lane * 4 + i];

    float vres[2];

#pragma unroll
    for (int b = 0; b < 2; ++b) {
        // ---- enc: dim h of point (p0 + 32b + q), 12 sin + 12 cos ----
        const float xd = xf[(p0 + 32 * b + q) * 2 + h];
        float sv[12], cv[12];
        {
            float r0 = __builtin_amdgcn_fractf(xd * 0.5f);     // j=0 seed
            sv[0] = __builtin_amdgcn_sinf(r0);
            cv[0] = __builtin_amdgcn_cosf(r0);
#pragma unroll
            for (int j = 1; j < 6; ++j) {
                float t = sv[j - 1] + sv[j - 1];
                sv[j] = t * cv[j - 1];
                cv[j] = fmaf(-t, sv[j - 1], 1.0f);
            }
            float r1 = __builtin_amdgcn_fractf(xd * 32.0f);    // j=6 seed
            sv[6] = __builtin_amdgcn_sinf(r1);
            cv[6] = __builtin_amdgcn_cosf(r1);
#pragma unroll
            for (int j = 7; j < 12; ++j) {
                float t = sv[j - 1] + sv[j - 1];
                sv[j] = t * cv[j - 1];
                cv[j] = fmaf(-t, sv[j - 1], 1.0f);
            }
        }

        // ---- B0 fragments: elem(t,e) = enc idx 8t+e (idx<12: sin, else cos) ----
        union { unsigned u[4]; short8 v; } bf0, bf1, bf2;
        bf0.u[0] = packbf(sv[0], sv[1]);  bf0.u[1] = packbf(sv[2], sv[3]);
        bf0.u[2] = packbf(sv[4], sv[5]);  bf0.u[3] = packbf(sv[6], sv[7]);
        bf1.u[0] = packbf(sv[8], sv[9]);  bf1.u[1] = packbf(sv[10], sv[11]);
        bf1.u[2] = packbf(cv[0], cv[1]);  bf1.u[3] = packbf(cv[2], cv[3]);
        bf2.u[0] = packbf(cv[4], cv[5]);  bf2.u[1] = packbf(cv[6], cv[7]);
        bf2.u[2] = packbf(cv[8], cv[9]);  bf2.u[3] = packbf(cv[10], cv[11]);

        // ---- layer 0: 3 MFMAs, C[32 chan][32 pt], acc in revolutions ----
        f32x16 zacc;
#pragma unroll
        for (int i = 0; i < 16; ++i) zacc[i] = 0.0f;
        f32x16 acc;
        acc = __builtin_amdgcn_mfma_f32_32x32x16_bf16(a0[0], bf0.v, zacc, 0, 0, 0);
        acc = __builtin_amdgcn_mfma_f32_32x32x16_bf16(a0[1], bf1.v, acc, 0, 0, 0);
        acc = __builtin_amdgcn_mfma_f32_32x32x16_bf16(a0[2], bf2.v, acc, 0, 0, 0);

        // ---- act (poly, FMA pipe) -> B1 fragments in-lane ----
        union { unsigned u[4]; short8 v; } b1a, b1b;
#pragma unroll
        for (int i = 0; i < 4; ++i)
            b1a.u[i] = packbf(sin2pi(acc[2 * i]), sin2pi(acc[2 * i + 1]));
#pragma unroll
        for (int i = 0; i < 4; ++i)
            b1b.u[i] = packbf(sin2pi(acc[8 + 2 * i]), sin2pi(acc[8 + 2 * i + 1]));

        // ---- layer 1: 2 MFMAs, acc1 in revolutions ----
        f32x16 acc1;
        acc1 = __builtin_amdgcn_mfma_f32_32x32x16_bf16(a1[0], b1a.v, zacc, 0, 0, 0);
        acc1 = __builtin_amdgcn_mfma_f32_32x32x16_bf16(a1[1], b1b.v, acc1, 0, 0, 0);

        // ---- act (poly) + W2 dot: reg r -> chan (r&3)+8*(r>>2)+4h ----
        float s0, s1, s2, s3;
        s0 = sin2pi(acc1[0]) * w2v[0].x;
        s0 = fmaf(sin2pi(acc1[1]), w2v[0].y, s0);
        s0 = fmaf(sin2pi(acc1[2]), w2v[0].z, s0);
        s0 = fmaf(sin2pi(acc1[3]), w2v[0].w, s0);
        s1 = sin2pi(acc1[4]) * w2v[1].x;
        s1 = fmaf(sin2pi(acc1[5]), w2v[1].y, s1);
        s1 = fmaf(sin2pi(acc1[6]), w2v[1].z, s1);
        s1 = fmaf(sin2pi(acc1[7]), w2v[1].w, s1);
        s2 = sin2pi(acc1[8]) * w2v[2].x;
        s2 = fmaf(sin2pi(acc1[9]), w2v[2].y, s2);
        s2 = fmaf(sin2pi(acc1[10]), w2v[2].z, s2);
        s2 = fmaf(sin2pi(acc1[11]), w2v[2].w, s2);
        s3 = sin2pi(acc1[12]) * w2v[3].x;
        s3 = fmaf(sin2pi(acc1[13]), w2v[3].y, s3);
        s3 = fmaf(sin2pi(acc1[14]), w2v[3].z, s3);
        s3 = fmaf(sin2pi(acc1[15]), w2v[3].w, s3);
        vres[b] = (s0 + s1) + (s2 + s3);
    }

    // ---- cross-half reduce (2 lanes per point) + coalesced store ----
    vres[0] += __shfl_xor(vres[0], 32, 64);
    vres[1] += __shfl_xor(vres[1], 32, 64);
    out[p0 + lane] = h ? vres[1] : vres[0];
}

extern "C" void kernel_launch(void* const* d_in, const int* in_sizes, int n_in,
                              void* d_out, int out_size, void* d_ws, size_t ws_size,
                              hipStream_t stream) {
    const float* xf = (const float*)d_in[0];
    const float* W0 = (const float*)d_in[1];
    const float* W1 = (const float*)d_in[2];
    const float* W2 = (const float*)d_in[3];
    float* out = (float*)d_out;
    uint4* ws = (uint4*)d_ws;

    const int n = in_sizes[0] / 2;
    build_frags<<<1, 64, 0, stream>>>(W0, W1, W2, ws);
    const int blocks = (n + THREADS - 1) / THREADS;
    siren_mfma_kernel<<<blocks, THREADS, 0, stream>>>(xf, ws, out, n);
}

// Round 12
// 32.939 us; speedup vs baseline: 1.3843x; 1.3843x over previous
//
#include <hip/hip_runtime.h>
#include <hip/hip_bf16.h>

// Siren fused, 32x32x16 MFMA, zero-LDS, double sigma-cancellation.
// R12: R8 structure (v_sin activations — R11 proved trans issue is cheap and
// the kernel is VALU-issue-bound), with the f32->bf16 packs replaced by a
// 3-inst branch-free round-half-up pack (v_add x2 + v_perm_b32) instead of
// __float22bfloat162_rn's ~10-inst software RNE sequence. 20 packs/lane/b-iter
// => predicted ~-8 us if the header pack was the hidden instruction bloat.

typedef short short8 __attribute__((ext_vector_type(8)));
typedef float f32x16 __attribute__((ext_vector_type(16)));

#define THREADS 256
#define INV2PI 0.15915494309189535f

// host/setup-side exact RNE pack (build_frags only, perf-irrelevant)
__device__ __forceinline__ unsigned packbf_rne(float lo, float hi) {
    union { __hip_bfloat162 h; unsigned u; } v;
    v.h = __float22bfloat162_rn(make_float2(lo, hi));
    return v.u;
}

// fast pack: round-half-up to bf16, pack pair. 3 VALU insts, branch-free.
// dst = { rh(hi), rh(lo) }, rh(x) = (bits(x)+0x8000)>>16.
// Differs from RNE only at exact half-ulp ties (+1 ulp16); inputs are finite.
__device__ __forceinline__ unsigned packbf(float lo, float hi) {
    unsigned a = __float_as_uint(lo) + 0x8000u;
    unsigned b = __float_as_uint(hi) + 0x8000u;
    return __builtin_amdgcn_perm(b, a, 0x07060302u);  // bytes {b3,b2,a3,a2}
}

// ---- bake per-lane A fragments (W^T scaled by 1/2pi), 32x32x16 shape ----
// ws (uint4): [0..191]   A0 frags, t=0..2 : elem e of lane(h,c) = W0[h*24+8t+e][c]/2pi
//             [192..319] A1 frags, t=0..1 : elem e = W1[(e&3)+8*(e>>2)+4h+16t][c]/2pi
//             [320..575] W2 per-lane 4x float4: w2v[i] = W2[8i+4h .. +3]
__global__ void build_frags(const float* __restrict__ W0,
                            const float* __restrict__ W1,
                            const float* __restrict__ W2,
                            uint4* __restrict__ ws) {
    int l = threadIdx.x;
    if (l >= 64) return;
    int h = l >> 5, c = l & 31;

#pragma unroll
    for (int t = 0; t < 3; ++t) {
        float ev[8];
#pragma unroll
        for (int e = 0; e < 8; ++e) ev[e] = W0[(h * 24 + 8 * t + e) * 32 + c] * INV2PI;
        ws[t * 64 + l] = make_uint4(packbf_rne(ev[0], ev[1]), packbf_rne(ev[2], ev[3]),
                                    packbf_rne(ev[4], ev[5]), packbf_rne(ev[6], ev[7]));
    }
#pragma unroll
    for (int t = 0; t < 2; ++t) {
        float ev[8];
#pragma unroll
        for (int e = 0; e < 8; ++e) {
            int k = (e & 3) + 8 * (e >> 2) + 4 * h + 16 * t;
            ev[e] = W1[k * 32 + c] * INV2PI;
        }
        ws[(3 + t) * 64 + l] = make_uint4(packbf_rne(ev[0], ev[1]), packbf_rne(ev[2], ev[3]),
                                          packbf_rne(ev[4], ev[5]), packbf_rne(ev[6], ev[7]));
    }
    float4* w2v = (float4*)(ws + 320);
#pragma unroll
    for (int i = 0; i < 4; ++i)
        w2v[l * 4 + i] = make_float4(W2[8 * i + 4 * h + 0], W2[8 * i + 4 * h + 1],
                                     W2[8 * i + 4 * h + 2], W2[8 * i + 4 * h + 3]);
}

__global__ __launch_bounds__(THREADS, 4) void siren_mfma_kernel(
    const float* __restrict__ xf,     // [N][2] flat
    const uint4* __restrict__ wf,
    float* __restrict__ out,
    int n)
{
    const int lane = threadIdx.x & 63;
    const int wid = threadIdx.x >> 6;
    const int q = lane & 31, h = lane >> 5;
    const int p0 = blockIdx.x * THREADS + wid * 64;
    if (p0 >= n) return;

    union U { uint4 u; short8 v; };
    short8 a0[3], a1[2];
#pragma unroll
    for (int t = 0; t < 3; ++t) { U tt; tt.u = wf[t * 64 + lane]; a0[t] = tt.v; }
#pragma unroll
    for (int t = 0; t < 2; ++t) { U tt; tt.u = wf[(3 + t) * 64 + lane]; a1[t] = tt.v; }
    float4 w2v[4];
#pragma unroll
    for (int i = 0; i < 4; ++i) w2v[i] = ((const float4*)(wf + 320))[lane * 4 + i];

    // shared zero C operand for the first MFMA of each chain
    f32x16 zacc;
#pragma unroll
    for (int i = 0; i < 16; ++i) zacc[i] = 0.0f;

    float vres[2];

#pragma unroll
    for (int b = 0; b < 2; ++b) {
        // ---- enc: dim h of point (p0 + 32b + q), 12 sin + 12 cos ----
        const float xd = xf[(p0 + 32 * b + q) * 2 + h];
        float sv[12], cv[12];
        {
            float r0 = __builtin_amdgcn_fractf(xd * 0.5f);     // j=0 seed
            sv[0] = __builtin_amdgcn_sinf(r0);
            cv[0] = __builtin_amdgcn_cosf(r0);
#pragma unroll
            for (int j = 1; j < 6; ++j) {
                float t = sv[j - 1] + sv[j - 1];
                sv[j] = t * cv[j - 1];
                cv[j] = fmaf(-t, sv[j - 1], 1.0f);
            }
            float r1 = __builtin_amdgcn_fractf(xd * 32.0f);    // j=6 seed
            sv[6] = __builtin_amdgcn_sinf(r1);
            cv[6] = __builtin_amdgcn_cosf(r1);
#pragma unroll
            for (int j = 7; j < 12; ++j) {
                float t = sv[j - 1] + sv[j - 1];
                sv[j] = t * cv[j - 1];
                cv[j] = fmaf(-t, sv[j - 1], 1.0f);
            }
        }

        // ---- B0 fragments: elem(t,e) = enc idx 8t+e (idx<12: sin, else cos) ----
        union { unsigned u[4]; short8 v; } bf0, bf1, bf2;
        bf0.u[0] = packbf(sv[0], sv[1]);  bf0.u[1] = packbf(sv[2], sv[3]);
        bf0.u[2] = packbf(sv[4], sv[5]);  bf0.u[3] = packbf(sv[6], sv[7]);
        bf1.u[0] = packbf(sv[8], sv[9]);  bf1.u[1] = packbf(sv[10], sv[11]);
        bf1.u[2] = packbf(cv[0], cv[1]);  bf1.u[3] = packbf(cv[2], cv[3]);
        bf2.u[0] = packbf(cv[4], cv[5]);  bf2.u[1] = packbf(cv[6], cv[7]);
        bf2.u[2] = packbf(cv[8], cv[9]);  bf2.u[3] = packbf(cv[10], cv[11]);

        // ---- layer 0: 3 MFMAs, C[32 chan][32 pt], acc in revolutions ----
        f32x16 acc;
        acc = __builtin_amdgcn_mfma_f32_32x32x16_bf16(a0[0], bf0.v, zacc, 0, 0, 0);
        acc = __builtin_amdgcn_mfma_f32_32x32x16_bf16(a0[1], bf1.v, acc, 0, 0, 0);
        acc = __builtin_amdgcn_mfma_f32_32x32x16_bf16(a0[2], bf2.v, acc, 0, 0, 0);

        // ---- act (bare v_sin, acc in revolutions) -> B1 fragments in-lane ----
        union { unsigned u[4]; short8 v; } b1a, b1b;
#pragma unroll
        for (int i = 0; i < 4; ++i)
            b1a.u[i] = packbf(__builtin_amdgcn_sinf(acc[2 * i]),
                              __builtin_amdgcn_sinf(acc[2 * i + 1]));
#pragma unroll
        for (int i = 0; i < 4; ++i)
            b1b.u[i] = packbf(__builtin_amdgcn_sinf(acc[8 + 2 * i]),
                              __builtin_amdgcn_sinf(acc[8 + 2 * i + 1]));

        // ---- layer 1: 2 MFMAs, acc1 in revolutions ----
        f32x16 acc1;
        acc1 = __builtin_amdgcn_mfma_f32_32x32x16_bf16(a1[0], b1a.v, zacc, 0, 0, 0);
        acc1 = __builtin_amdgcn_mfma_f32_32x32x16_bf16(a1[1], b1b.v, acc1, 0, 0, 0);

        // ---- act + W2 dot: reg r -> chan (r&3)+8*(r>>2)+4h -> w2v[r>>2][r&3] ----
        float s0, s1, s2, s3;
        s0 = __builtin_amdgcn_sinf(acc1[0]) * w2v[0].x;
        s0 = fmaf(__builtin_amdgcn_sinf(acc1[1]), w2v[0].y, s0);
        s0 = fmaf(__builtin_amdgcn_sinf(acc1[2]), w2v[0].z, s0);
        s0 = fmaf(__builtin_amdgcn_sinf(acc1[3]), w2v[0].w, s0);
        s1 = __builtin_amdgcn_sinf(acc1[4]) * w2v[1].x;
        s1 = fmaf(__builtin_amdgcn_sinf(acc1[5]), w2v[1].y, s1);
        s1 = fmaf(__builtin_amdgcn_sinf(acc1[6]), w2v[1].z, s1);
        s1 = fmaf(__builtin_amdgcn_sinf(acc1[7]), w2v[1].w, s1);
        s2 = __builtin_amdgcn_sinf(acc1[8]) * w2v[2].x;
        s2 = fmaf(__builtin_amdgcn_sinf(acc1[9]), w2v[2].y, s2);
        s2 = fmaf(__builtin_amdgcn_sinf(acc1[10]), w2v[2].z, s2);
        s2 = fmaf(__builtin_amdgcn_sinf(acc1[11]), w2v[2].w, s2);
        s3 = __builtin_amdgcn_sinf(acc1[12]) * w2v[3].x;
        s3 = fmaf(__builtin_amdgcn_sinf(acc1[13]), w2v[3].y, s3);
        s3 = fmaf(__builtin_amdgcn_sinf(acc1[14]), w2v[3].z, s3);
        s3 = fmaf(__builtin_amdgcn_sinf(acc1[15]), w2v[3].w, s3);
        vres[b] = (s0 + s1) + (s2 + s3);
    }

    // ---- cross-half reduce (2 lanes per point) + coalesced store ----
    vres[0] += __shfl_xor(vres[0], 32, 64);
    vres[1] += __shfl_xor(vres[1], 32, 64);
    out[p0 + lane] = h ? vres[1] : vres[0];
}

extern "C" void kernel_launch(void* const* d_in, const int* in_sizes, int n_in,
                              void* d_out, int out_size, void* d_ws, size_t ws_size,
                              hipStream_t stream) {
    const float* xf = (const float*)d_in[0];
    const float* W0 = (const float*)d_in[1];
    const float* W1 = (const float*)d_in[2];
    const float* W2 = (const float*)d_in[3];
    float* out = (float*)d_out;
    uint4* ws = (uint4*)d_ws;

    const int n = in_sizes[0] / 2;
    build_frags<<<1, 64, 0, stream>>>(W0, W1, W2, ws);
    const int blocks = (n + THREADS - 1) / THREADS;
    siren_mfma_kernel<<<blocks, THREADS, 0, stream>>>(xf, ws, out, n);
}

// Round 14
// 30.654 us; speedup vs baseline: 1.4874x; 1.0745x over previous
//
#include <hip/hip_runtime.h>
#include <hip/hip_bf16.h>
#include <hip/hip_fp16.h>

// Siren fused, 32x32x16 MFMA, zero-LDS, double sigma-cancellation.
// R14: R13 with the cvt_pkrtz type fixed (builtin returns __fp16 ext-vector).
// Datapath bf16 -> fp16: v_cvt_pkrtz_f16_f32 is a single-inst HW packed
// convert (real builtin), replacing the 3-inst bf16 pack (40 packs/lane).
// mfma_f32_32x32x16_f16 has the same shape + C/D layout (dtype-independent),
// so both kappa maps are unchanged. fp16 RTZ (2^-10) is more precise than
// bf16 RNE (2^-9) for all values in play -> absmax should drop.

typedef _Float16 half8 __attribute__((ext_vector_type(8)));
typedef __fp16 fp16x2 __attribute__((ext_vector_type(2)));
typedef float f32x16 __attribute__((ext_vector_type(16)));

#define THREADS 256
#define INV2PI 0.15915494309189535f

// single-inst packed f32->fp16 (RTZ): dst = {h16(lo), h16(hi)}
__device__ __forceinline__ unsigned packh(float lo, float hi) {
    union { fp16x2 h; unsigned u; } v;
    v.h = __builtin_amdgcn_cvt_pkrtz(lo, hi);
    return v.u;
}

// setup-side RNE pack (perf-irrelevant)
__device__ __forceinline__ unsigned packh_rne(float lo, float hi) {
    union { _Float16 h[2]; unsigned u; } v;
    v.h[0] = (_Float16)lo;
    v.h[1] = (_Float16)hi;
    return v.u;
}

// ---- bake per-lane A fragments (W^T scaled by 1/2pi), fp16, 32x32x16 ----
// ws (uint4): [0..191]   A0 frags, t=0..2 : elem e of lane(h,c) = W0[h*24+8t+e][c]/2pi
//             [192..319] A1 frags, t=0..1 : elem e = W1[(e&3)+8*(e>>2)+4h+16t][c]/2pi
//             [320..575] W2 per-lane 4x float4: w2v[i] = W2[8i+4h .. +3]
__global__ void build_frags(const float* __restrict__ W0,
                            const float* __restrict__ W1,
                            const float* __restrict__ W2,
                            uint4* __restrict__ ws) {
    int l = threadIdx.x;
    if (l >= 64) return;
    int h = l >> 5, c = l & 31;

#pragma unroll
    for (int t = 0; t < 3; ++t) {
        float ev[8];
#pragma unroll
        for (int e = 0; e < 8; ++e) ev[e] = W0[(h * 24 + 8 * t + e) * 32 + c] * INV2PI;
        ws[t * 64 + l] = make_uint4(packh_rne(ev[0], ev[1]), packh_rne(ev[2], ev[3]),
                                    packh_rne(ev[4], ev[5]), packh_rne(ev[6], ev[7]));
    }
#pragma unroll
    for (int t = 0; t < 2; ++t) {
        float ev[8];
#pragma unroll
        for (int e = 0; e < 8; ++e) {
            int k = (e & 3) + 8 * (e >> 2) + 4 * h + 16 * t;
            ev[e] = W1[k * 32 + c] * INV2PI;
        }
        ws[(3 + t) * 64 + l] = make_uint4(packh_rne(ev[0], ev[1]), packh_rne(ev[2], ev[3]),
                                          packh_rne(ev[4], ev[5]), packh_rne(ev[6], ev[7]));
    }
    float4* w2v = (float4*)(ws + 320);
#pragma unroll
    for (int i = 0; i < 4; ++i)
        w2v[l * 4 + i] = make_float4(W2[8 * i + 4 * h + 0], W2[8 * i + 4 * h + 1],
                                     W2[8 * i + 4 * h + 2], W2[8 * i + 4 * h + 3]);
}

__global__ __launch_bounds__(THREADS, 4) void siren_mfma_kernel(
    const float* __restrict__ xf,     // [N][2] flat
    const uint4* __restrict__ wf,
    float* __restrict__ out,
    int n)
{
    const int lane = threadIdx.x & 63;
    const int wid = threadIdx.x >> 6;
    const int q = lane & 31, h = lane >> 5;
    const int p0 = blockIdx.x * THREADS + wid * 64;
    if (p0 >= n) return;

    union U { uint4 u; half8 v; };
    half8 a0[3], a1[2];
#pragma unroll
    for (int t = 0; t < 3; ++t) { U tt; tt.u = wf[t * 64 + lane]; a0[t] = tt.v; }
#pragma unroll
    for (int t = 0; t < 2; ++t) { U tt; tt.u = wf[(3 + t) * 64 + lane]; a1[t] = tt.v; }
    float4 w2v[4];
#pragma unroll
    for (int i = 0; i < 4; ++i) w2v[i] = ((const float4*)(wf + 320))[lane * 4 + i];

    // shared zero C operand for the first MFMA of each chain
    f32x16 zacc;
#pragma unroll
    for (int i = 0; i < 16; ++i) zacc[i] = 0.0f;

    float vres[2];

#pragma unroll
    for (int b = 0; b < 2; ++b) {
        // ---- enc: dim h of point (p0 + 32b + q), 12 sin + 12 cos ----
        const float xd = xf[(p0 + 32 * b + q) * 2 + h];
        float sv[12], cv[12];
        {
            float r0 = __builtin_amdgcn_fractf(xd * 0.5f);     // j=0 seed
            sv[0] = __builtin_amdgcn_sinf(r0);
            cv[0] = __builtin_amdgcn_cosf(r0);
#pragma unroll
            for (int j = 1; j < 6; ++j) {
                float t = sv[j - 1] + sv[j - 1];
                sv[j] = t * cv[j - 1];
                cv[j] = fmaf(-t, sv[j - 1], 1.0f);
            }
            float r1 = __builtin_amdgcn_fractf(xd * 32.0f);    // j=6 seed
            sv[6] = __builtin_amdgcn_sinf(r1);
            cv[6] = __builtin_amdgcn_cosf(r1);
#pragma unroll
            for (int j = 7; j < 12; ++j) {
                float t = sv[j - 1] + sv[j - 1];
                sv[j] = t * cv[j - 1];
                cv[j] = fmaf(-t, sv[j - 1], 1.0f);
            }
        }

        // ---- B0 fragments: elem(t,e) = enc idx 8t+e (idx<12: sin, else cos) ----
        union { unsigned u[4]; half8 v; } bf0, bf1, bf2;
        bf0.u[0] = packh(sv[0], sv[1]);  bf0.u[1] = packh(sv[2], sv[3]);
        bf0.u[2] = packh(sv[4], sv[5]);  bf0.u[3] = packh(sv[6], sv[7]);
        bf1.u[0] = packh(sv[8], sv[9]);  bf1.u[1] = packh(sv[10], sv[11]);
        bf1.u[2] = packh(cv[0], cv[1]);  bf1.u[3] = packh(cv[2], cv[3]);
        bf2.u[0] = packh(cv[4], cv[5]);  bf2.u[1] = packh(cv[6], cv[7]);
        bf2.u[2] = packh(cv[8], cv[9]);  bf2.u[3] = packh(cv[10], cv[11]);

        // ---- layer 0: 3 MFMAs, C[32 chan][32 pt], acc in revolutions ----
        f32x16 acc;
        acc = __builtin_amdgcn_mfma_f32_32x32x16_f16(a0[0], bf0.v, zacc, 0, 0, 0);
        acc = __builtin_amdgcn_mfma_f32_32x32x16_f16(a0[1], bf1.v, acc, 0, 0, 0);
        acc = __builtin_amdgcn_mfma_f32_32x32x16_f16(a0[2], bf2.v, acc, 0, 0, 0);

        // ---- act (bare v_sin, acc in revolutions) -> B1 fragments in-lane ----
        union { unsigned u[4]; half8 v; } b1a, b1b;
#pragma unroll
        for (int i = 0; i < 4; ++i)
            b1a.u[i] = packh(__builtin_amdgcn_sinf(acc[2 * i]),
                             __builtin_amdgcn_sinf(acc[2 * i + 1]));
#pragma unroll
        for (int i = 0; i < 4; ++i)
            b1b.u[i] = packh(__builtin_amdgcn_sinf(acc[8 + 2 * i]),
                             __builtin_amdgcn_sinf(acc[8 + 2 * i + 1]));

        // ---- layer 1: 2 MFMAs, acc1 in revolutions ----
        f32x16 acc1;
        acc1 = __builtin_amdgcn_mfma_f32_32x32x16_f16(a1[0], b1a.v, zacc, 0, 0, 0);
        acc1 = __builtin_amdgcn_mfma_f32_32x32x16_f16(a1[1], b1b.v, acc1, 0, 0, 0);

        // ---- act + W2 dot: reg r -> chan (r&3)+8*(r>>2)+4h -> w2v[r>>2][r&3] ----
        float s0, s1, s2, s3;
        s0 = __builtin_amdgcn_sinf(acc1[0]) * w2v[0].x;
        s0 = fmaf(__builtin_amdgcn_sinf(acc1[1]), w2v[0].y, s0);
        s0 = fmaf(__builtin_amdgcn_sinf(acc1[2]), w2v[0].z, s0);
        s0 = fmaf(__builtin_amdgcn_sinf(acc1[3]), w2v[0].w, s0);
        s1 = __builtin_amdgcn_sinf(acc1[4]) * w2v[1].x;
        s1 = fmaf(__builtin_amdgcn_sinf(acc1[5]), w2v[1].y, s1);
        s1 = fmaf(__builtin_amdgcn_sinf(acc1[6]), w2v[1].z, s1);
        s1 = fmaf(__builtin_amdgcn_sinf(acc1[7]), w2v[1].w, s1);
        s2 = __builtin_amdgcn_sinf(acc1[8]) * w2v[2].x;
        s2 = fmaf(__builtin_amdgcn_sinf(acc1[9]), w2v[2].y, s2);
        s2 = fmaf(__builtin_amdgcn_sinf(acc1[10]), w2v[2].z, s2);
        s2 = fmaf(__builtin_amdgcn_sinf(acc1[11]), w2v[2].w, s2);
        s3 = __builtin_amdgcn_sinf(acc1[12]) * w2v[3].x;
        s3 = fmaf(__builtin_amdgcn_sinf(acc1[13]), w2v[3].y, s3);
        s3 = fmaf(__builtin_amdgcn_sinf(acc1[14]), w2v[3].z, s3);
        s3 = fmaf(__builtin_amdgcn_sinf(acc1[15]), w2v[3].w, s3);
        vres[b] = (s0 + s1) + (s2 + s3);
    }

    // ---- cross-half reduce (2 lanes per point) + coalesced store ----
    vres[0] += __shfl_xor(vres[0], 32, 64);
    vres[1] += __shfl_xor(vres[1], 32, 64);
    out[p0 + lane] = h ? vres[1] : vres[0];
}

extern "C" void kernel_launch(void* const* d_in, const int* in_sizes, int n_in,
                              void* d_out, int out_size, void* d_ws, size_t ws_size,
                              hipStream_t stream) {
    const float* xf = (const float*)d_in[0];
    const float* W0 = (const float*)d_in[1];
    const float* W1 = (const float*)d_in[2];
    const float* W2 = (const float*)d_in[3];
    float* out = (float*)d_out;
    uint4* ws = (uint4*)d_ws;

    const int n = in_sizes[0] / 2;
    build_frags<<<1, 64, 0, stream>>>(W0, W1, W2, ws);
    const int blocks = (n + THREADS - 1) / THREADS;
    siren_mfma_kernel<<<blocks, THREADS, 0, stream>>>(xf, ws, out, n);
}

// Round 15
// 30.554 us; speedup vs baseline: 1.4923x; 1.0033x over previous
//
#include <hip/hip_runtime.h>
#include <hip/hip_bf16.h>
#include <hip/hip_fp16.h>

// Siren fused, 32x32x16 fp16 MFMA, zero-LDS, double sigma-cancellation.
// R15: explicit 2-stream software pipeline. The two 32-point blocks (b0,b1)
// are independent; R14's sequential source order let the compiler serialize
// them (VGPR_Count=48 => one long dependency chain, ~50% stall). Phases are
// now interleaved so each stream's VALU fills the other's MFMA/trans shadow:
//   enc0 -> L0(0) -> enc1 -> L0(1) -> act0+L1(0) -> act1+L1(1) -> dot0 -> dot1
// Also: fracts dropped (x in [0,1); v_sin/v_cos accept +-256 revolutions).

typedef _Float16 half8 __attribute__((ext_vector_type(8)));
typedef __fp16 fp16x2 __attribute__((ext_vector_type(2)));
typedef float f32x16 __attribute__((ext_vector_type(16)));

#define THREADS 256
#define INV2PI 0.15915494309189535f

// single-inst packed f32->fp16 (RTZ)
__device__ __forceinline__ unsigned packh(float lo, float hi) {
    union { fp16x2 h; unsigned u; } v;
    v.h = __builtin_amdgcn_cvt_pkrtz(lo, hi);
    return v.u;
}

__device__ __forceinline__ unsigned packh_rne(float lo, float hi) {
    union { _Float16 h[2]; unsigned u; } v;
    v.h[0] = (_Float16)lo;
    v.h[1] = (_Float16)hi;
    return v.u;
}

// enc chain: 12 sin + 12 cos of pi*2^j*xd, via 2 seeds + 10 double-angle steps.
// No fract: xd in [0,1) so xd*0.5 < 0.5 rev; xd*32 < 32 rev (v_sin ok to 256).
__device__ __forceinline__ void enc_chain(float xd, float sv[12], float cv[12]) {
    sv[0] = __builtin_amdgcn_sinf(xd * 0.5f);
    cv[0] = __builtin_amdgcn_cosf(xd * 0.5f);
#pragma unroll
    for (int j = 1; j < 6; ++j) {
        float t = sv[j - 1] + sv[j - 1];
        sv[j] = t * cv[j - 1];
        cv[j] = fmaf(-t, sv[j - 1], 1.0f);
    }
    sv[6] = __builtin_amdgcn_sinf(xd * 32.0f);
    cv[6] = __builtin_amdgcn_cosf(xd * 32.0f);
#pragma unroll
    for (int j = 7; j < 12; ++j) {
        float t = sv[j - 1] + sv[j - 1];
        sv[j] = t * cv[j - 1];
        cv[j] = fmaf(-t, sv[j - 1], 1.0f);
    }
}

// ---- bake per-lane A fragments (W^T scaled by 1/2pi), fp16, 32x32x16 ----
// ws (uint4): [0..191]   A0 frags, t=0..2 : elem e of lane(h,c) = W0[h*24+8t+e][c]/2pi
//             [192..319] A1 frags, t=0..1 : elem e = W1[(e&3)+8*(e>>2)+4h+16t][c]/2pi
//             [320..575] W2 per-lane 4x float4: w2v[i] = W2[8i+4h .. +3]
__global__ void build_frags(const float* __restrict__ W0,
                            const float* __restrict__ W1,
                            const float* __restrict__ W2,
                            uint4* __restrict__ ws) {
    int l = threadIdx.x;
    if (l >= 64) return;
    int h = l >> 5, c = l & 31;

#pragma unroll
    for (int t = 0; t < 3; ++t) {
        float ev[8];
#pragma unroll
        for (int e = 0; e < 8; ++e) ev[e] = W0[(h * 24 + 8 * t + e) * 32 + c] * INV2PI;
        ws[t * 64 + l] = make_uint4(packh_rne(ev[0], ev[1]), packh_rne(ev[2], ev[3]),
                                    packh_rne(ev[4], ev[5]), packh_rne(ev[6], ev[7]));
    }
#pragma unroll
    for (int t = 0; t < 2; ++t) {
        float ev[8];
#pragma unroll
        for (int e = 0; e < 8; ++e) {
            int k = (e & 3) + 8 * (e >> 2) + 4 * h + 16 * t;
            ev[e] = W1[k * 32 + c] * INV2PI;
        }
        ws[(3 + t) * 64 + l] = make_uint4(packh_rne(ev[0], ev[1]), packh_rne(ev[2], ev[3]),
                                          packh_rne(ev[4], ev[5]), packh_rne(ev[6], ev[7]));
    }
    float4* w2v = (float4*)(ws + 320);
#pragma unroll
    for (int i = 0; i < 4; ++i)
        w2v[l * 4 + i] = make_float4(W2[8 * i + 4 * h + 0], W2[8 * i + 4 * h + 1],
                                     W2[8 * i + 4 * h + 2], W2[8 * i + 4 * h + 3]);
}

__global__ __launch_bounds__(THREADS, 4) void siren_mfma_kernel(
    const float* __restrict__ xf,     // [N][2] flat
    const uint4* __restrict__ wf,
    float* __restrict__ out,
    int n)
{
    const int lane = threadIdx.x & 63;
    const int wid = threadIdx.x >> 6;
    const int q = lane & 31, h = lane >> 5;
    const int p0 = blockIdx.x * THREADS + wid * 64;
    if (p0 >= n) return;

    // both x loads in flight
    const float xd0 = xf[(p0 + q) * 2 + h];
    const float xd1 = xf[(p0 + 32 + q) * 2 + h];

    union U { uint4 u; half8 v; };
    half8 a0[3], a1[2];
#pragma unroll
    for (int t = 0; t < 3; ++t) { U tt; tt.u = wf[t * 64 + lane]; a0[t] = tt.v; }
#pragma unroll
    for (int t = 0; t < 2; ++t) { U tt; tt.u = wf[(3 + t) * 64 + lane]; a1[t] = tt.v; }

    f32x16 zacc;
#pragma unroll
    for (int i = 0; i < 16; ++i) zacc[i] = 0.0f;

    // ================= stream 0: enc + pack + L0 =================
    union F { unsigned u[4]; half8 v; };
    F bf00, bf01, bf02;
    {
        float sv[12], cv[12];
        enc_chain(xd0, sv, cv);
        bf00.u[0] = packh(sv[0], sv[1]);  bf00.u[1] = packh(sv[2], sv[3]);
        bf00.u[2] = packh(sv[4], sv[5]);  bf00.u[3] = packh(sv[6], sv[7]);
        bf01.u[0] = packh(sv[8], sv[9]);  bf01.u[1] = packh(sv[10], sv[11]);
        bf01.u[2] = packh(cv[0], cv[1]);  bf01.u[3] = packh(cv[2], cv[3]);
        bf02.u[0] = packh(cv[4], cv[5]);  bf02.u[1] = packh(cv[6], cv[7]);
        bf02.u[2] = packh(cv[8], cv[9]);  bf02.u[3] = packh(cv[10], cv[11]);
    }
    f32x16 accA;
    accA = __builtin_amdgcn_mfma_f32_32x32x16_f16(a0[0], bf00.v, zacc, 0, 0, 0);
    accA = __builtin_amdgcn_mfma_f32_32x32x16_f16(a0[1], bf01.v, accA, 0, 0, 0);
    accA = __builtin_amdgcn_mfma_f32_32x32x16_f16(a0[2], bf02.v, accA, 0, 0, 0);

    // ================= stream 1: enc + pack + L0 (fills L0(0) shadow) =====
    F bf10, bf11, bf12;
    {
        float sv[12], cv[12];
        enc_chain(xd1, sv, cv);
        bf10.u[0] = packh(sv[0], sv[1]);  bf10.u[1] = packh(sv[2], sv[3]);
        bf10.u[2] = packh(sv[4], sv[5]);  bf10.u[3] = packh(sv[6], sv[7]);
        bf11.u[0] = packh(sv[8], sv[9]);  bf11.u[1] = packh(sv[10], sv[11]);
        bf11.u[2] = packh(cv[0], cv[1]);  bf11.u[3] = packh(cv[2], cv[3]);
        bf12.u[0] = packh(cv[4], cv[5]);  bf12.u[1] = packh(cv[6], cv[7]);
        bf12.u[2] = packh(cv[8], cv[9]);  bf12.u[3] = packh(cv[10], cv[11]);
    }
    f32x16 accB;
    accB = __builtin_amdgcn_mfma_f32_32x32x16_f16(a0[0], bf10.v, zacc, 0, 0, 0);
    accB = __builtin_amdgcn_mfma_f32_32x32x16_f16(a0[1], bf11.v, accB, 0, 0, 0);
    accB = __builtin_amdgcn_mfma_f32_32x32x16_f16(a0[2], bf12.v, accB, 0, 0, 0);

    // ======= act0 + L1(0) (sins fill L0(1) shadow) =======
    F b1a0, b1b0;
#pragma unroll
    for (int i = 0; i < 4; ++i)
        b1a0.u[i] = packh(__builtin_amdgcn_sinf(accA[2 * i]),
                          __builtin_amdgcn_sinf(accA[2 * i + 1]));
#pragma unroll
    for (int i = 0; i < 4; ++i)
        b1b0.u[i] = packh(__builtin_amdgcn_sinf(accA[8 + 2 * i]),
                          __builtin_amdgcn_sinf(accA[8 + 2 * i + 1]));
    f32x16 acc1A;
    acc1A = __builtin_amdgcn_mfma_f32_32x32x16_f16(a1[0], b1a0.v, zacc, 0, 0, 0);
    acc1A = __builtin_amdgcn_mfma_f32_32x32x16_f16(a1[1], b1b0.v, acc1A, 0, 0, 0);

    // ======= act1 + L1(1) (sins fill L1(0) shadow) =======
    F b1a1, b1b1;
#pragma unroll
    for (int i = 0; i < 4; ++i)
        b1a1.u[i] = packh(__builtin_amdgcn_sinf(accB[2 * i]),
                          __builtin_amdgcn_sinf(accB[2 * i + 1]));
#pragma unroll
    for (int i = 0; i < 4; ++i)
        b1b1.u[i] = packh(__builtin_amdgcn_sinf(accB[8 + 2 * i]),
                          __builtin_amdgcn_sinf(accB[8 + 2 * i + 1]));
    f32x16 acc1B;
    acc1B = __builtin_amdgcn_mfma_f32_32x32x16_f16(a1[0], b1a1.v, zacc, 0, 0, 0);
    acc1B = __builtin_amdgcn_mfma_f32_32x32x16_f16(a1[1], b1b1.v, acc1B, 0, 0, 0);

    // ======= W2 dots (dot0 fills L1(1) shadow) =======
    float4 w2v[4];
#pragma unroll
    for (int i = 0; i < 4; ++i) w2v[i] = ((const float4*)(wf + 320))[lane * 4 + i];

    float vres0, vres1;
    {
        float s0, s1, s2, s3;
        s0 = __builtin_amdgcn_sinf(acc1A[0]) * w2v[0].x;
        s0 = fmaf(__builtin_amdgcn_sinf(acc1A[1]), w2v[0].y, s0);
        s0 = fmaf(__builtin_amdgcn_sinf(acc1A[2]), w2v[0].z, s0);
        s0 = fmaf(__builtin_amdgcn_sinf(acc1A[3]), w2v[0].w, s0);
        s1 = __builtin_amdgcn_sinf(acc1A[4]) * w2v[1].x;
        s1 = fmaf(__builtin_amdgcn_sinf(acc1A[5]), w2v[1].y, s1);
        s1 = fmaf(__builtin_amdgcn_sinf(acc1A[6]), w2v[1].z, s1);
        s1 = fmaf(__builtin_amdgcn_sinf(acc1A[7]), w2v[1].w, s1);
        s2 = __builtin_amdgcn_sinf(acc1A[8]) * w2v[2].x;
        s2 = fmaf(__builtin_amdgcn_sinf(acc1A[9]), w2v[2].y, s2);
        s2 = fmaf(__builtin_amdgcn_sinf(acc1A[10]), w2v[2].z, s2);
        s2 = fmaf(__builtin_amdgcn_sinf(acc1A[11]), w2v[2].w, s2);
        s3 = __builtin_amdgcn_sinf(acc1A[12]) * w2v[3].x;
        s3 = fmaf(__builtin_amdgcn_sinf(acc1A[13]), w2v[3].y, s3);
        s3 = fmaf(__builtin_amdgcn_sinf(acc1A[14]), w2v[3].z, s3);
        s3 = fmaf(__builtin_amdgcn_sinf(acc1A[15]), w2v[3].w, s3);
        vres0 = (s0 + s1) + (s2 + s3);
    }
    {
        float s0, s1, s2, s3;
        s0 = __builtin_amdgcn_sinf(acc1B[0]) * w2v[0].x;
        s0 = fmaf(__builtin_amdgcn_sinf(acc1B[1]), w2v[0].y, s0);
        s0 = fmaf(__builtin_amdgcn_sinf(acc1B[2]), w2v[0].z, s0);
        s0 = fmaf(__builtin_amdgcn_sinf(acc1B[3]), w2v[0].w, s0);
        s1 = __builtin_amdgcn_sinf(acc1B[4]) * w2v[1].x;
        s1 = fmaf(__builtin_amdgcn_sinf(acc1B[5]), w2v[1].y, s1);
        s1 = fmaf(__builtin_amdgcn_sinf(acc1B[6]), w2v[1].z, s1);
        s1 = fmaf(__builtin_amdgcn_sinf(acc1B[7]), w2v[1].w, s1);
        s2 = __builtin_amdgcn_sinf(acc1B[8]) * w2v[2].x;
        s2 = fmaf(__builtin_amdgcn_sinf(acc1B[9]), w2v[2].y, s2);
        s2 = fmaf(__builtin_amdgcn_sinf(acc1B[10]), w2v[2].z, s2);
        s2 = fmaf(__builtin_amdgcn_sinf(acc1B[11]), w2v[2].w, s2);
        s3 = __builtin_amdgcn_sinf(acc1B[12]) * w2v[3].x;
        s3 = fmaf(__builtin_amdgcn_sinf(acc1B[13]), w2v[3].y, s3);
        s3 = fmaf(__builtin_amdgcn_sinf(acc1B[14]), w2v[3].z, s3);
        s3 = fmaf(__builtin_amdgcn_sinf(acc1B[15]), w2v[3].w, s3);
        vres1 = (s0 + s1) + (s2 + s3);
    }

    // ---- cross-half reduce (2 lanes per point) + coalesced store ----
    vres0 += __shfl_xor(vres0, 32, 64);
    vres1 += __shfl_xor(vres1, 32, 64);
    out[p0 + lane] = h ? vres1 : vres0;
}

extern "C" void kernel_launch(void* const* d_in, const int* in_sizes, int n_in,
                              void* d_out, int out_size, void* d_ws, size_t ws_size,
                              hipStream_t stream) {
    const float* xf = (const float*)d_in[0];
    const float* W0 = (const float*)d_in[1];
    const float* W1 = (const float*)d_in[2];
    const float* W2 = (const float*)d_in[3];
    float* out = (float*)d_out;
    uint4* ws = (uint4*)d_ws;

    const int n = in_sizes[0] / 2;
    build_frags<<<1, 64, 0, stream>>>(W0, W1, W2, ws);
    const int blocks = (n + THREADS - 1) / THREADS;
    siren_mfma_kernel<<<blocks, THREADS, 0, stream>>>(xf, ws, out, n);
}

// Round 16
// 30.156 us; speedup vs baseline: 1.5120x; 1.0132x over previous
//
#include <hip/hip_runtime.h>
#include <hip/hip_bf16.h>
#include <hip/hip_fp16.h>

// Siren fused, 32x32x16 fp16 MFMA, zero-LDS, TRIPLE sigma-cancellation.
// R16: the W2 dot + cross-lane reduce replaced by a third MFMA with W2 baked
// into row 0 (stream 0) / row 4 (stream 1) of the A operand. The L1-act sins
// already form a valid B-fragment in-lane (e-slot e of frag t = acc1 reg
// e+8t), and the MFMA's K-sum does the cross-h reduce in hardware -> zero
// ds_bpermute at the tail, fully coalesced lane-local store.

typedef _Float16 half8 __attribute__((ext_vector_type(8)));
typedef __fp16 fp16x2 __attribute__((ext_vector_type(2)));
typedef float f32x16 __attribute__((ext_vector_type(16)));

#define THREADS 256
#define INV2PI 0.15915494309189535f

// single-inst packed f32->fp16 (RTZ)
__device__ __forceinline__ unsigned packh(float lo, float hi) {
    union { fp16x2 h; unsigned u; } v;
    v.h = __builtin_amdgcn_cvt_pkrtz(lo, hi);
    return v.u;
}

__device__ __forceinline__ unsigned packh_rne(float lo, float hi) {
    union { _Float16 h[2]; unsigned u; } v;
    v.h[0] = (_Float16)lo;
    v.h[1] = (_Float16)hi;
    return v.u;
}

// enc chain: 12 sin + 12 cos of pi*2^j*xd via 2 seeds + 10 double-angle steps.
// No fract: xd in [0,1); v_sin/v_cos accept +-256 revolutions.
__device__ __forceinline__ void enc_chain(float xd, float sv[12], float cv[12]) {
    sv[0] = __builtin_amdgcn_sinf(xd * 0.5f);
    cv[0] = __builtin_amdgcn_cosf(xd * 0.5f);
#pragma unroll
    for (int j = 1; j < 6; ++j) {
        float t = sv[j - 1] + sv[j - 1];
        sv[j] = t * cv[j - 1];
        cv[j] = fmaf(-t, sv[j - 1], 1.0f);
    }
    sv[6] = __builtin_amdgcn_sinf(xd * 32.0f);
    cv[6] = __builtin_amdgcn_cosf(xd * 32.0f);
#pragma unroll
    for (int j = 7; j < 12; ++j) {
        float t = sv[j - 1] + sv[j - 1];
        sv[j] = t * cv[j - 1];
        cv[j] = fmaf(-t, sv[j - 1], 1.0f);
    }
}

// ---- bake per-lane A fragments, fp16, 32x32x16 ----
// ws (uint4): [0..191]   A0 frags, t=0..2 : elem e of lane(h,c) = W0[h*24+8t+e][c]/2pi
//             [192..319] A1 frags, t=0..1 : elem e = W1[kap(h,t,e)][c]/2pi
//             [320..447] dotA0 frags, t=0..1: elem e = (c==0) ? W2[kap(h,t,e)] : 0
//             [448..575] dotA1 frags, t=0..1: elem e = (c==4) ? W2[kap(h,t,e)] : 0
// kap(h,t,e) = (e&3) + 8*(e>>2) + 4h + 16t
__global__ void build_frags(const float* __restrict__ W0,
                            const float* __restrict__ W1,
                            const float* __restrict__ W2,
                            uint4* __restrict__ ws) {
    int l = threadIdx.x;
    if (l >= 64) return;
    int h = l >> 5, c = l & 31;

#pragma unroll
    for (int t = 0; t < 3; ++t) {
        float ev[8];
#pragma unroll
        for (int e = 0; e < 8; ++e) ev[e] = W0[(h * 24 + 8 * t + e) * 32 + c] * INV2PI;
        ws[t * 64 + l] = make_uint4(packh_rne(ev[0], ev[1]), packh_rne(ev[2], ev[3]),
                                    packh_rne(ev[4], ev[5]), packh_rne(ev[6], ev[7]));
    }
#pragma unroll
    for (int t = 0; t < 2; ++t) {
        float ev[8];
#pragma unroll
        for (int e = 0; e < 8; ++e) {
            int k = (e & 3) + 8 * (e >> 2) + 4 * h + 16 * t;
            ev[e] = W1[k * 32 + c] * INV2PI;
        }
        ws[(3 + t) * 64 + l] = make_uint4(packh_rne(ev[0], ev[1]), packh_rne(ev[2], ev[3]),
                                          packh_rne(ev[4], ev[5]), packh_rne(ev[6], ev[7]));
    }
    // dot fragments: W2 in row 0 (stream 0) / row 4 (stream 1)
#pragma unroll
    for (int s = 0; s < 2; ++s)
#pragma unroll
        for (int t = 0; t < 2; ++t) {
            float ev[8];
#pragma unroll
            for (int e = 0; e < 8; ++e) {
                int k = (e & 3) + 8 * (e >> 2) + 4 * h + 16 * t;
                ev[e] = (c == 4 * s) ? W2[k] : 0.0f;
            }
            ws[(5 + 2 * s + t) * 64 + l] = make_uint4(packh_rne(ev[0], ev[1]), packh_rne(ev[2], ev[3]),
                                                      packh_rne(ev[4], ev[5]), packh_rne(ev[6], ev[7]));
        }
}

__global__ __launch_bounds__(THREADS, 4) void siren_mfma_kernel(
    const float* __restrict__ xf,     // [N][2] flat
    const uint4* __restrict__ wf,
    float* __restrict__ out,
    int n)
{
    const int lane = threadIdx.x & 63;
    const int wid = threadIdx.x >> 6;
    const int q = lane & 31, h = lane >> 5;
    const int p0 = blockIdx.x * THREADS + wid * 64;
    if (p0 >= n) return;

    const float xd0 = xf[(p0 + q) * 2 + h];
    const float xd1 = xf[(p0 + 32 + q) * 2 + h];

    union U { uint4 u; half8 v; };
    half8 a0[3], a1[2], d0[2], d1[2];
#pragma unroll
    for (int t = 0; t < 3; ++t) { U tt; tt.u = wf[t * 64 + lane]; a0[t] = tt.v; }
#pragma unroll
    for (int t = 0; t < 2; ++t) { U tt; tt.u = wf[(3 + t) * 64 + lane]; a1[t] = tt.v; }
#pragma unroll
    for (int t = 0; t < 2; ++t) { U tt; tt.u = wf[(5 + t) * 64 + lane]; d0[t] = tt.v; }
#pragma unroll
    for (int t = 0; t < 2; ++t) { U tt; tt.u = wf[(7 + t) * 64 + lane]; d1[t] = tt.v; }

    f32x16 zacc;
#pragma unroll
    for (int i = 0; i < 16; ++i) zacc[i] = 0.0f;

    union F { unsigned u[4]; half8 v; };

    // ===== stream 0: enc + L0 =====
    F bf00, bf01, bf02;
    {
        float sv[12], cv[12];
        enc_chain(xd0, sv, cv);
        bf00.u[0] = packh(sv[0], sv[1]);  bf00.u[1] = packh(sv[2], sv[3]);
        bf00.u[2] = packh(sv[4], sv[5]);  bf00.u[3] = packh(sv[6], sv[7]);
        bf01.u[0] = packh(sv[8], sv[9]);  bf01.u[1] = packh(sv[10], sv[11]);
        bf01.u[2] = packh(cv[0], cv[1]);  bf01.u[3] = packh(cv[2], cv[3]);
        bf02.u[0] = packh(cv[4], cv[5]);  bf02.u[1] = packh(cv[6], cv[7]);
        bf02.u[2] = packh(cv[8], cv[9]);  bf02.u[3] = packh(cv[10], cv[11]);
    }
    f32x16 accA;
    accA = __builtin_amdgcn_mfma_f32_32x32x16_f16(a0[0], bf00.v, zacc, 0, 0, 0);
    accA = __builtin_amdgcn_mfma_f32_32x32x16_f16(a0[1], bf01.v, accA, 0, 0, 0);
    accA = __builtin_amdgcn_mfma_f32_32x32x16_f16(a0[2], bf02.v, accA, 0, 0, 0);

    // ===== stream 1: enc + L0 =====
    F bf10, bf11, bf12;
    {
        float sv[12], cv[12];
        enc_chain(xd1, sv, cv);
        bf10.u[0] = packh(sv[0], sv[1]);  bf10.u[1] = packh(sv[2], sv[3]);
        bf10.u[2] = packh(sv[4], sv[5]);  bf10.u[3] = packh(sv[6], sv[7]);
        bf11.u[0] = packh(sv[8], sv[9]);  bf11.u[1] = packh(sv[10], sv[11]);
        bf11.u[2] = packh(cv[0], cv[1]);  bf11.u[3] = packh(cv[2], cv[3]);
        bf12.u[0] = packh(cv[4], cv[5]);  bf12.u[1] = packh(cv[6], cv[7]);
        bf12.u[2] = packh(cv[8], cv[9]);  bf12.u[3] = packh(cv[10], cv[11]);
    }
    f32x16 accB;
    accB = __builtin_amdgcn_mfma_f32_32x32x16_f16(a0[0], bf10.v, zacc, 0, 0, 0);
    accB = __builtin_amdgcn_mfma_f32_32x32x16_f16(a0[1], bf11.v, accB, 0, 0, 0);
    accB = __builtin_amdgcn_mfma_f32_32x32x16_f16(a0[2], bf12.v, accB, 0, 0, 0);

    // ===== act0 + L1(0) =====
    F b1a0, b1b0;
#pragma unroll
    for (int i = 0; i < 4; ++i)
        b1a0.u[i] = packh(__builtin_amdgcn_sinf(accA[2 * i]),
                          __builtin_amdgcn_sinf(accA[2 * i + 1]));
#pragma unroll
    for (int i = 0; i < 4; ++i)
        b1b0.u[i] = packh(__builtin_amdgcn_sinf(accA[8 + 2 * i]),
                          __builtin_amdgcn_sinf(accA[8 + 2 * i + 1]));
    f32x16 acc1A;
    acc1A = __builtin_amdgcn_mfma_f32_32x32x16_f16(a1[0], b1a0.v, zacc, 0, 0, 0);
    acc1A = __builtin_amdgcn_mfma_f32_32x32x16_f16(a1[1], b1b0.v, acc1A, 0, 0, 0);

    // ===== act1 + L1(1) =====
    F b1a1, b1b1;
#pragma unroll
    for (int i = 0; i < 4; ++i)
        b1a1.u[i] = packh(__builtin_amdgcn_sinf(accB[2 * i]),
                          __builtin_amdgcn_sinf(accB[2 * i + 1]));
#pragma unroll
    for (int i = 0; i < 4; ++i)
        b1b1.u[i] = packh(__builtin_amdgcn_sinf(accB[8 + 2 * i]),
                          __builtin_amdgcn_sinf(accB[8 + 2 * i + 1]));
    f32x16 acc1B;
    acc1B = __builtin_amdgcn_mfma_f32_32x32x16_f16(a1[0], b1a1.v, zacc, 0, 0, 0);
    acc1B = __builtin_amdgcn_mfma_f32_32x32x16_f16(a1[1], b1b1.v, acc1B, 0, 0, 0);

    // ===== act2 + dot-MFMA (W2 in row 0 / row 4; K-sum = cross-h reduce) =====
    F b2a0, b2b0;
#pragma unroll
    for (int i = 0; i < 4; ++i)
        b2a0.u[i] = packh(__builtin_amdgcn_sinf(acc1A[2 * i]),
                          __builtin_amdgcn_sinf(acc1A[2 * i + 1]));
#pragma unroll
    for (int i = 0; i < 4; ++i)
        b2b0.u[i] = packh(__builtin_amdgcn_sinf(acc1A[8 + 2 * i]),
                          __builtin_amdgcn_sinf(acc1A[8 + 2 * i + 1]));
    f32x16 accDA;
    accDA = __builtin_amdgcn_mfma_f32_32x32x16_f16(d0[0], b2a0.v, zacc, 0, 0, 0);
    accDA = __builtin_amdgcn_mfma_f32_32x32x16_f16(d0[1], b2b0.v, accDA, 0, 0, 0);

    F b2a1, b2b1;
#pragma unroll
    for (int i = 0; i < 4; ++i)
        b2a1.u[i] = packh(__builtin_amdgcn_sinf(acc1B[2 * i]),
                          __builtin_amdgcn_sinf(acc1B[2 * i + 1]));
#pragma unroll
    for (int i = 0; i < 4; ++i)
        b2b1.u[i] = packh(__builtin_amdgcn_sinf(acc1B[8 + 2 * i]),
                          __builtin_amdgcn_sinf(acc1B[8 + 2 * i + 1]));
    f32x16 accDB;
    accDB = __builtin_amdgcn_mfma_f32_32x32x16_f16(d1[0], b2a1.v, zacc, 0, 0, 0);
    accDB = __builtin_amdgcn_mfma_f32_32x32x16_f16(d1[1], b2b1.v, accDB, 0, 0, 0);

    // ===== store: reg 0 of lane (h,q) = C[row 4h][q] = dot of point 32h+q =====
    out[p0 + 32 * h + q] = h ? accDB[0] : accDA[0];
}

extern "C" void kernel_launch(void* const* d_in, const int* in_sizes, int n_in,
                              void* d_out, int out_size, void* d_ws, size_t ws_size,
                              hipStream_t stream) {
    const float* xf = (const float*)d_in[0];
    const float* W0 = (const float*)d_in[1];
    const float* W1 = (const float*)d_in[2];
    const float* W2 = (const float*)d_in[3];
    float* out = (float*)d_out;
    uint4* ws = (uint4*)d_ws;

    const int n = in_sizes[0] / 2;
    build_frags<<<1, 64, 0, stream>>>(W0, W1, W2, ws);
    const int blocks = (n + THREADS - 1) / THREADS;
    siren_mfma_kernel<<<blocks, THREADS, 0, stream>>>(xf, ws, out, n);
}